// Round 4
// baseline (3081.897 us; speedup 1.0000x reference)
//
#include <hip/hip_runtime.h>
#include <hip/hip_bf16.h>
#include <math.h>

// SpeakerEncoderLSTM: T=40, B=64, VN=36, A_DIM=V_DIM=2048, H=1024, DOT=256
// Strategy:
//  - logits = w.(W_v^T target) + (b_v.target)  [second term softmax-invariant -> dropped]
//  - u = h @ (W_h^T W_v) = h @ Mt^T  (Mt precomputed once per launch)
//  - ga[t] = a_t @ Wia^T hoisted out of the t-loop as ONE large GEMM (k_ga):
//    input-only, so it runs at full-device MFMA throughput instead of being
//    latency-exposed on the 40-step sequential chain.
//  - per step: K1: u = h@Mt^T+u0 ; gpart = h@Whh^T + ga[t]   (K=1024 only)
//              K2: attention (logits/softmax/feature) per-batch block, fp32
//              K3: gates = gpart + feature@Wif^T + bias -> LSTM elementwise
//  - all GEMMs: bf16 MFMA 16x16x32, fp32 accum, BM=64 BN=64 BK=64, dbuf LDS

typedef unsigned short u16;
typedef __attribute__((ext_vector_type(4))) int i32x4;
typedef __attribute__((ext_vector_type(4))) float f32x4;
typedef __attribute__((ext_vector_type(8))) short s16x8;
typedef __attribute__((ext_vector_type(4))) unsigned short u16x4;

__device__ __forceinline__ u16 f2b(float f) {
  unsigned int x = __float_as_uint(f);
  unsigned int r = (x + 0x7fffu + ((x >> 16) & 1u)) >> 16;
  return (u16)r;
}

__device__ __forceinline__ float b2f(u16 x) {
  return __uint_as_float((unsigned int)x << 16);
}

__device__ __forceinline__ float tanh_fast(float x) {
  float e = __expf(2.f * x);
  return 1.f - 2.f / (e + 1.f);
}

__device__ __forceinline__ float sigmoid_fast(float x) {
  return 1.f / (1.f + __expf(-x));
}

// ---------------- prologue: weight conversions -------------------------------
// unit = 4 elements. segments: W_ih(4194304) W_hh(1048576) a(1310720)
// W_e2d(262144) bias(1024) zero h_b/c(16384); total 6833152
__global__ __launch_bounds__(256) void k_prep(
    const float* __restrict__ W_ih, const float* __restrict__ W_hh,
    const float* __restrict__ a, const float* __restrict__ W_e2d,
    const float* __restrict__ b_ih, const float* __restrict__ b_hh,
    u16* __restrict__ Wia, u16* __restrict__ Wif, u16* __restrict__ Whh,
    u16* __restrict__ We2d, u16* __restrict__ a_b, float* __restrict__ bias,
    u16* __restrict__ h_b, float* __restrict__ c) {
  const size_t stride = (size_t)gridDim.x * blockDim.x;
  for (size_t i = (size_t)blockIdx.x * blockDim.x + threadIdx.x; i < 6833152u; i += stride) {
    if (i < 4194304u) {
      size_t e = i * 4;
      int n = (int)(e >> 12), k = (int)(e & 4095);
      float4 v = *(const float4*)(W_ih + e);
      u16x4 o; o.x = f2b(v.x); o.y = f2b(v.y); o.z = f2b(v.z); o.w = f2b(v.w);
      if (k < 2048) *(u16x4*)(Wia + (size_t)n * 2048 + k) = o;
      else          *(u16x4*)(Wif + (size_t)n * 2048 + (k - 2048)) = o;
    } else if (i < 5242880u) {
      size_t e = (i - 4194304u) * 4;
      float4 v = *(const float4*)(W_hh + e);
      u16x4 o; o.x = f2b(v.x); o.y = f2b(v.y); o.z = f2b(v.z); o.w = f2b(v.w);
      *(u16x4*)(Whh + e) = o;
    } else if (i < 6553600u) {
      size_t e = (i - 5242880u) * 4;
      float4 v = *(const float4*)(a + e);
      u16x4 o; o.x = f2b(v.x); o.y = f2b(v.y); o.z = f2b(v.z); o.w = f2b(v.w);
      *(u16x4*)(a_b + e) = o;
    } else if (i < 6815744u) {
      size_t e = (i - 6553600u) * 4;
      float4 v = *(const float4*)(W_e2d + e);
      u16x4 o; o.x = f2b(v.x); o.y = f2b(v.y); o.z = f2b(v.z); o.w = f2b(v.w);
      *(u16x4*)(We2d + e) = o;
    } else if (i < 6816768u) {
      size_t e = (i - 6815744u) * 4;
      float4 x = *(const float4*)(b_ih + e);
      float4 y = *(const float4*)(b_hh + e);
      float4 o; o.x = x.x + y.x; o.y = x.y + y.y; o.z = x.z + y.z; o.w = x.w + y.w;
      *(float4*)(bias + e) = o;
    } else {
      size_t e = (i - 6816768u) * 4;
      u16x4 z = {0, 0, 0, 0};
      *(u16x4*)(h_b + e) = z;
      float4 zf; zf.x = zf.y = zf.z = zf.w = 0.f;
      *(float4*)(c + e) = zf;
    }
  }
}

// Mt[v][k] = sum_d W_h[d][k] * W_v[d][v]  (bf16 out); u0[v] = sum_d b_h[d]*W_v[d][v]
__global__ __launch_bounds__(256) void k_mt(
    const float* __restrict__ W_h, const float* __restrict__ W_v,
    const float* __restrict__ b_h, u16* __restrict__ Mt, float* __restrict__ u0) {
  __shared__ float sWh[64][32];
  const int k0 = blockIdx.x * 32, v0 = blockIdx.y * 256;
  const int tid = threadIdx.x;
  const int v = v0 + tid;
  float acc[32];
#pragma unroll
  for (int kk = 0; kk < 32; kk++) acc[kk] = 0.f;
  float au0 = 0.f;
  for (int d0 = 0; d0 < 256; d0 += 64) {
    __syncthreads();
    for (int jj = tid; jj < 2048; jj += 256) {
      int dl = jj >> 5, kl = jj & 31;
      sWh[dl][kl] = W_h[(size_t)(d0 + dl) * 1024 + k0 + kl];
    }
    __syncthreads();
    for (int dd = 0; dd < 64; dd++) {
      float wvv = W_v[(size_t)(d0 + dd) * 2048 + v];
      au0 += b_h[d0 + dd] * wvv;
#pragma unroll
      for (int kk = 0; kk < 32; kk++) acc[kk] += sWh[dd][kk] * wvv;
    }
  }
#pragma unroll
  for (int kk = 0; kk < 32; kk++) Mt[(size_t)v * 1024 + k0 + kk] = f2b(acc[kk]);
  if (k0 == 0) u0[v] = au0;
}

// ---------------- shared MFMA tile compute ----------------------------------
__device__ __forceinline__ void mfma_tile(const u16 (*sA)[72], const u16 (*sB)[72],
                                          int wv, int lane, f32x4 acc[4]) {
  const int mrow = 16 * wv + (lane & 15);
  const int nbase = lane & 15;
  const int koff = (lane >> 4) * 8;
#pragma unroll
  for (int s = 0; s < 2; s++) {
    s16x8 af = *(const s16x8*)&sA[mrow][s * 32 + koff];
#pragma unroll
    for (int f = 0; f < 4; f++) {
      s16x8 bv = *(const s16x8*)&sB[16 * f + nbase][s * 32 + koff];
      acc[f] = __builtin_amdgcn_mfma_f32_16x16x32_bf16(af, bv, acc[f], 0, 0, 0);
    }
  }
}

// ---------------- ga = a @ Wia^T for ALL steps (one big GEMM) ----------------
// grid (64, 40): block (nb, t). rows m = 64 batch rows of step t; cols nb*64.
__global__ __launch_bounds__(256) void k_ga(
    const u16* __restrict__ a_b, const u16* __restrict__ Wia,
    u16* __restrict__ ga) {
  __shared__ u16 sA[2][64][72];
  __shared__ u16 sB[2][64][72];
  const int nb = blockIdx.x, t = blockIdx.y, tid = threadIdx.x;
  const int wv = tid >> 6, lane = tid & 63;
  const int n0 = nb * 64;
  const int r = tid >> 2, ko = (tid & 3) * 16;
  const u16* arow = a_b + ((size_t)t * 64 + r) * 2048;
  const u16* brow = Wia + (size_t)(n0 + r) * 2048;

  f32x4 acc[4] = {};
  i32x4 ra0, ra1, rb0, rb1;

  auto load_tile = [&](int kt) {
    int kg = kt * 64 + ko;
    ra0 = *(const i32x4*)(arow + kg);
    ra1 = *(const i32x4*)(arow + kg + 8);
    rb0 = *(const i32x4*)(brow + kg);
    rb1 = *(const i32x4*)(brow + kg + 8);
  };
  auto write_tile = [&](int buf) {
    *(i32x4*)&sA[buf][r][ko] = ra0;
    *(i32x4*)&sA[buf][r][ko + 8] = ra1;
    *(i32x4*)&sB[buf][r][ko] = rb0;
    *(i32x4*)&sB[buf][r][ko + 8] = rb1;
  };

  load_tile(0);
  write_tile(0);
  __syncthreads();
  for (int kt = 0; kt < 32; kt++) {
    if (kt + 1 < 32) load_tile(kt + 1);
    mfma_tile(sA[kt & 1], sB[kt & 1], wv, lane, acc);
    if (kt + 1 < 32) write_tile((kt + 1) & 1);
    __syncthreads();
  }

  const int col = lane & 15, mbase = 16 * wv + (lane >> 4) * 4;
#pragma unroll
  for (int f = 0; f < 4; f++) {
    int n = n0 + 16 * f + col;
#pragma unroll
    for (int rg = 0; rg < 4; rg++) {
      int m = mbase + rg;
      ga[((size_t)t * 64 + m) * 4096 + n] = f2b(acc[f][rg]);
    }
  }
}

// ---------------- step 1: u = h@Mt^T + u0 ; gpart = h@Whh^T + ga[t] ----------
// blocks 0..63 : gpart tile (n0=bid*64)   blocks 64..95: u tile
// uniform K=1024 (16 tiles), A = h for every block.
__global__ __launch_bounds__(256) void k_step1(
    const u16* __restrict__ h_b, const u16* __restrict__ Whh,
    const u16* __restrict__ Mt, const float* __restrict__ u0,
    const u16* __restrict__ ga, float* __restrict__ gpart,
    float* __restrict__ uout, int t) {
  __shared__ u16 sA[2][64][72];
  __shared__ u16 sB[2][64][72];
  const int bid = blockIdx.x, tid = threadIdx.x;
  const int wv = tid >> 6, lane = tid & 63;
  const bool isU = bid >= 64;
  const int n0 = isU ? (bid - 64) * 64 : bid * 64;
  const int r = tid >> 2, ko = (tid & 3) * 16;
  const u16* arow = h_b + (size_t)r * 1024;
  const u16* brow = (isU ? Mt : Whh) + (size_t)(n0 + r) * 1024;

  f32x4 acc[4] = {};
  i32x4 ra0, ra1, rb0, rb1;

  auto load_tile = [&](int kt) {
    int kg = kt * 64 + ko;
    ra0 = *(const i32x4*)(arow + kg);
    ra1 = *(const i32x4*)(arow + kg + 8);
    rb0 = *(const i32x4*)(brow + kg);
    rb1 = *(const i32x4*)(brow + kg + 8);
  };
  auto write_tile = [&](int buf) {
    *(i32x4*)&sA[buf][r][ko] = ra0;
    *(i32x4*)&sA[buf][r][ko + 8] = ra1;
    *(i32x4*)&sB[buf][r][ko] = rb0;
    *(i32x4*)&sB[buf][r][ko + 8] = rb1;
  };

  load_tile(0);
  write_tile(0);
  __syncthreads();
  for (int kt = 0; kt < 16; kt++) {
    if (kt + 1 < 16) load_tile(kt + 1);
    mfma_tile(sA[kt & 1], sB[kt & 1], wv, lane, acc);
    if (kt + 1 < 16) write_tile((kt + 1) & 1);
    __syncthreads();
  }

  const int col = lane & 15, mbase = 16 * wv + (lane >> 4) * 4;
#pragma unroll
  for (int f = 0; f < 4; f++) {
    int n = n0 + 16 * f + col;
#pragma unroll
    for (int rg = 0; rg < 4; rg++) {
      int m = mbase + rg;
      float v = acc[f][rg];
      if (isU) uout[m * 2048 + n] = v + u0[n];
      else     gpart[m * 4096 + n] = v + b2f(ga[((size_t)t * 64 + m) * 4096 + n]);
    }
  }
}

// ---------------- step 2: attention (one block per batch row) ----------------
__global__ __launch_bounds__(1024) void k_step2(
    const float* __restrict__ w, const float* __restrict__ u,
    u16* __restrict__ feat, int t) {
  const int b = blockIdx.x, tid = threadIdx.x;
  const int wv = tid >> 6, lane = tid & 63;
  __shared__ float su[2048];
  __shared__ float sl[64];
  const float* wt = w + ((size_t)(t * 64 + b)) * (36 * 2048);

  for (int i = tid; i < 2048; i += 1024) su[i] = u[b * 2048 + i];
  __syncthreads();

  // logits[n] = w_t[b][n] . u[b]
  for (int n = wv; n < 36; n += 16) {
    const float4* wr4 = (const float4*)(wt + n * 2048);
    float acc = 0.f;
#pragma unroll
    for (int it = 0; it < 8; it++) {
      int q = it * 64 + lane;
      float4 x = wr4[q];
      int v = q * 4;
      acc += x.x * su[v] + x.y * su[v + 1] + x.z * su[v + 2] + x.w * su[v + 3];
    }
#pragma unroll
    for (int o = 32; o > 0; o >>= 1) acc += __shfl_xor(acc, o);
    if (lane == 0) sl[n] = acc;
  }
  __syncthreads();

  // softmax over 36 on wave 0
  if (wv == 0) {
    float l = (lane < 36) ? sl[lane] : -3.0e38f;
    float m = l;
#pragma unroll
    for (int o = 32; o > 0; o >>= 1) m = fmaxf(m, __shfl_xor(m, o));
    float e = (lane < 36) ? __expf(l - m) : 0.f;
    float s = e;
#pragma unroll
    for (int o = 32; o > 0; o >>= 1) s += __shfl_xor(s, o);
    if (lane < 36) sl[lane] = e / s;
  }
  __syncthreads();

  // feature[v] = sum_n attn[n]*w_t[b][n][v]  (w_t now L2-hot)
  for (int v = tid; v < 2048; v += 1024) {
    float acc = 0.f;
#pragma unroll 4
    for (int n = 0; n < 36; n++) acc += sl[n] * wt[n * 2048 + v];
    feat[b * 2048 + v] = f2b(acc);
  }
}

// ---------------- step 3: gates += feature@Wif^T ; LSTM elementwise ----------
// 64 blocks; block bid owns hidden j-tile [bid*16, bid*16+16), B rows are the
// 64 gate rows {g*1024 + bid*16 + jj}; fragment f == gate f.
__global__ __launch_bounds__(256) void k_step3(
    const u16* __restrict__ feat, const u16* __restrict__ Wif,
    const float* __restrict__ gpart, const float* __restrict__ bias,
    float* __restrict__ c, u16* __restrict__ h_b,
    float* __restrict__ out_ctx, int t) {
  __shared__ u16 sA[2][64][72];
  __shared__ u16 sB[2][64][72];
  const int bid = blockIdx.x, tid = threadIdx.x;
  const int wv = tid >> 6, lane = tid & 63;
  const int r = tid >> 2, ko = (tid & 3) * 16;
  const int gg = r >> 4, jj = r & 15;
  const u16* brow = Wif + ((size_t)(gg * 1024 + bid * 16 + jj)) * 2048;
  const u16* arow = feat + r * 2048;

  f32x4 acc[4] = {};
  i32x4 ra0, ra1, rb0, rb1;

  auto load_tile = [&](int kt) {
    int kg = kt * 64 + ko;
    ra0 = *(const i32x4*)(arow + kg);
    ra1 = *(const i32x4*)(arow + kg + 8);
    rb0 = *(const i32x4*)(brow + kg);
    rb1 = *(const i32x4*)(brow + kg + 8);
  };
  auto write_tile = [&](int buf) {
    *(i32x4*)&sA[buf][r][ko] = ra0;
    *(i32x4*)&sA[buf][r][ko + 8] = ra1;
    *(i32x4*)&sB[buf][r][ko] = rb0;
    *(i32x4*)&sB[buf][r][ko + 8] = rb1;
  };

  load_tile(0);
  write_tile(0);
  __syncthreads();
  for (int kt = 0; kt < 32; kt++) {
    if (kt + 1 < 32) load_tile(kt + 1);
    mfma_tile(sA[kt & 1], sB[kt & 1], wv, lane, acc);
    if (kt + 1 < 32) write_tile((kt + 1) & 1);
    __syncthreads();
  }

  const int col = lane & 15, j = bid * 16 + col;
  const int mbase = 16 * wv + (lane >> 4) * 4;
#pragma unroll
  for (int rg = 0; rg < 4; rg++) {
    int m = mbase + rg;
    float ig = acc[0][rg] + gpart[m * 4096 + j] + bias[j];
    float fg = acc[1][rg] + gpart[m * 4096 + 1024 + j] + bias[1024 + j];
    float gt = acc[2][rg] + gpart[m * 4096 + 2048 + j] + bias[2048 + j];
    float og = acc[3][rg] + gpart[m * 4096 + 3072 + j] + bias[3072 + j];
    float cn = sigmoid_fast(fg) * c[m * 1024 + j] + sigmoid_fast(ig) * tanh_fast(gt);
    float hn = sigmoid_fast(og) * tanh_fast(cn);
    c[m * 1024 + j] = cn;
    h_b[m * 1024 + j] = f2b(hn);
    out_ctx[((size_t)m * 40 + t) * 1024 + j] = hn;
  }
}

// ---------------- epilogue: decoder_init = tanh(h@We2d^T + b) ; c_T copy -----
__global__ __launch_bounds__(256) void k_epi(
    const u16* __restrict__ h_b, const u16* __restrict__ We2d,
    const float* __restrict__ b_e2d, const float* __restrict__ c,
    float* __restrict__ out) {
  const int bid = blockIdx.x, tid = threadIdx.x;
  if (bid >= 16) {
    const float4* src = (const float4*)c;
    float4* dst = (float4*)(out + 2686976);
    for (int i = (bid - 16) * 256 + tid; i < 16384; i += 4096) dst[i] = src[i];
    return;
  }
  __shared__ u16 sA[2][64][72];
  __shared__ u16 sB[2][64][72];
  const int tid2 = tid;
  const int wv = tid2 >> 6, lane = tid2 & 63;
  const int r = tid2 >> 2, ko = (tid2 & 3) * 16;
  const int n0 = bid * 64;

  f32x4 acc[4] = {};
  i32x4 ra0, ra1, rb0, rb1;
  auto load_tile = [&](int kt) {
    int kg = kt * 64 + ko;
    ra0 = *(const i32x4*)(h_b + r * 1024 + kg);
    ra1 = *(const i32x4*)(h_b + r * 1024 + kg + 8);
    rb0 = *(const i32x4*)(We2d + (size_t)(n0 + r) * 1024 + kg);
    rb1 = *(const i32x4*)(We2d + (size_t)(n0 + r) * 1024 + kg + 8);
  };
  auto write_tile = [&](int buf) {
    *(i32x4*)&sA[buf][r][ko] = ra0;
    *(i32x4*)&sA[buf][r][ko + 8] = ra1;
    *(i32x4*)&sB[buf][r][ko] = rb0;
    *(i32x4*)&sB[buf][r][ko + 8] = rb1;
  };

  load_tile(0);
  write_tile(0);
  __syncthreads();
  for (int kt = 0; kt < 16; kt++) {
    if (kt + 1 < 16) load_tile(kt + 1);
    mfma_tile(sA[kt & 1], sB[kt & 1], wv, lane, acc);
    if (kt + 1 < 16) write_tile((kt + 1) & 1);
    __syncthreads();
  }

  const int col = lane & 15, mbase = 16 * wv + (lane >> 4) * 4;
#pragma unroll
  for (int f = 0; f < 4; f++) {
    int n = n0 + 16 * f + col;
#pragma unroll
    for (int rg = 0; rg < 4; rg++) {
      int m = mbase + rg;
      out[2621440 + m * 1024 + n] = tanh_fast(acc[f][rg] + b_e2d[n]);
    }
  }
}

// ---------------- launch -----------------------------------------------------
extern "C" void kernel_launch(void* const* d_in, const int* in_sizes, int n_in,
                              void* d_out, int out_size, void* d_ws, size_t ws_size,
                              hipStream_t stream) {
  (void)in_sizes; (void)n_in; (void)out_size; (void)ws_size;
  const float* a     = (const float*)d_in[0];   // [40,64,2048]
  const float* w     = (const float*)d_in[1];   // [40,64,36,2048]
  const float* W_h   = (const float*)d_in[2];   // [256,1024]
  const float* b_h   = (const float*)d_in[3];   // [256]
  const float* W_v   = (const float*)d_in[4];   // [256,2048]
  // d_in[5] = b_v: softmax shift-invariant -> unused
  const float* W_ih  = (const float*)d_in[6];   // [4096,4096]
  const float* b_ih  = (const float*)d_in[7];   // [4096]
  const float* W_hh  = (const float*)d_in[8];   // [4096,1024]
  const float* b_hh  = (const float*)d_in[9];   // [4096]
  const float* W_e2d = (const float*)d_in[10];  // [1024,1024]
  const float* b_e2d = (const float*)d_in[11];  // [1024]
  float* out = (float*)d_out;

  char* ws = (char*)d_ws;
  u16*   Wia   = (u16*)(ws + 0);           // 4096x2048 bf16
  u16*   Wif   = (u16*)(ws + 16777216);    // 4096x2048 bf16
  u16*   Whh   = (u16*)(ws + 33554432);    // 4096x1024 bf16
  u16*   Mt    = (u16*)(ws + 41943040);    // 2048x1024 bf16
  u16*   We2d  = (u16*)(ws + 46137344);    // 1024x1024 bf16
  u16*   a_b   = (u16*)(ws + 48234496);    // 40x64x2048 bf16
  u16*   ga    = (u16*)(ws + 58720256);    // 40x64x4096 bf16
  float* u0    = (float*)(ws + 79691776);  // 2048
  float* bias  = (float*)(ws + 79699968);  // 4096
  u16*   h_b   = (u16*)(ws + 79716352);    // 64x1024 bf16
  float* c     = (float*)(ws + 79847424);  // 64x1024 f32
  float* u     = (float*)(ws + 80109568);  // 64x2048 f32
  float* gpart = (float*)(ws + 80633856);  // 64x4096 f32
  u16*   feat  = (u16*)(ws + 81682432);    // 64x2048 bf16
  // total ws: ~81.9 MB

  k_prep<<<dim3(2048), dim3(256), 0, stream>>>(W_ih, W_hh, a, W_e2d, b_ih, b_hh,
                                               Wia, Wif, Whh, We2d, a_b, bias, h_b, c);
  k_mt<<<dim3(32, 8), dim3(256), 0, stream>>>(W_h, W_v, b_h, Mt, u0);
  k_ga<<<dim3(64, 40), dim3(256), 0, stream>>>(a_b, Wia, ga);

  for (int t = 0; t < 40; t++) {
    k_step1<<<dim3(96), dim3(256), 0, stream>>>(h_b, Whh, Mt, u0, ga, gpart, u, t);
    k_step2<<<dim3(64), dim3(1024), 0, stream>>>(w, u, feat, t);
    k_step3<<<dim3(64), dim3(256), 0, stream>>>(feat, Wif, gpart, bias, c, h_b, out, t);
  }
  k_epi<<<dim3(32), dim3(256), 0, stream>>>(h_b, We2d, b_e2d, c, out);
}